// Round 9
// baseline (13921.991 us; speedup 1.0000x reference)
//
#include <hip/hip_runtime.h>
#include <cmath>

#define BATCH 128
#define TLEN  256
#define HDIM  1024
#define CDIM  10
#define NT    512
#define NWG   256

typedef unsigned long long u64;
typedef unsigned int u32;
typedef u64 ull2 __attribute__((ext_vector_type(2)));

// h state, double buffered, k-major, u64 = 2 packed floats: g_hx[buf][j][b/2].
// WRITES: relaxed agent-scope sc1 (write-through -> L2 never dirty). READS:
// plain cached loads (L1/L2 shared), made safe by the acquire-agent fence
// (clean-L2 invalidate) after each grid barrier.
__device__ u64 g_hx[2][HDIM][BATCH / 2];

__device__ __forceinline__ float4 ld4(const float* p) { return *(const float4*)p; }

__device__ __forceinline__ void astore(u64* p, u64 v) {
    __hip_atomic_store(p, v, __ATOMIC_RELAXED, __HIP_MEMORY_SCOPE_AGENT);
}
__device__ __forceinline__ float4 two2f4(u64 a, u64 b) {
    u64 t[2] = {a, b}; float4 f; __builtin_memcpy(&f, t, 16); return f;
}
__device__ __forceinline__ u64 f2toU(float a, float b) {
    float2 f = make_float2(a, b); u64 v; __builtin_memcpy(&v, &f, 8); return v;
}
__device__ __forceinline__ float2 u2f2(u64 v) {
    float2 f; __builtin_memcpy(&f, &v, 8); return f;
}

// Grid barrier (round-6/7/8 proven). __syncthreads drains vmcnt(0) => sc1
// h-stores are at the coherence point before arrive. Acquire fence after:
// buffer_inv only (L2 never dirty). Bounded spin: bugs -> wrong, never hang.
__device__ __forceinline__ void gbar(u32* ctr, int slot) {
    __syncthreads();
    if (threadIdx.x == 0) {
        __hip_atomic_fetch_add(&ctr[slot], 1u, __ATOMIC_RELAXED, __HIP_MEMORY_SCOPE_AGENT);
        int guard = 0;
        while (__hip_atomic_load(&ctr[slot], __ATOMIC_RELAXED, __HIP_MEMORY_SCOPE_AGENT) < NWG
               && ++guard < (1 << 22)) {
            __builtin_amdgcn_s_sleep(2);
        }
    }
    __syncthreads();
    __builtin_amdgcn_fence(__ATOMIC_ACQUIRE, "agent");
}

#define FMA4(d, s, v) do { (d).x = fmaf((s), (v).x, (d).x); (d).y = fmaf((s), (v).y, (d).y); \
                           (d).z = fmaf((s), (v).z, (d).z); (d).w = fmaf((s), (v).w, (d).w); } while (0)

// Block: 8 j x 64 b. 8 waves: wave = jq*2 + kh; k-subset {c*32 + kk*16 + kh*8 + ks}.
// NO per-chunk barriers (round-8 lesson: 32 lockstep barriers/step defeat
// wave overlap): h is read DIRECTLY from global into double-buffered regs
// (static indices; round-3 scratch lesson), W from persistent LDS. The only
// per-step syncs: one __syncthreads for the cross-kh LDS exchange + gbar.
__global__ void __launch_bounds__(NT, 1)
lstm_fused(const float* __restrict__ x,
           const float* __restrict__ Wgx, const float* __restrict__ Wgh, const float* __restrict__ bg,
           const float* __restrict__ Wix, const float* __restrict__ Wih, const float* __restrict__ bi,
           const float* __restrict__ Wfx, const float* __restrict__ Wfh, const float* __restrict__ bf,
           const float* __restrict__ Wox, const float* __restrict__ Woh, const float* __restrict__ bo,
           const float* __restrict__ Wph, const float* __restrict__ bp,
           u32* __restrict__ bar, float* __restrict__ out)
{
    __shared__ float  sW[8][HDIM][4];   // [j_local][k][gate], 128 KB, persistent
    __shared__ float4 sS[4][64][2];     // cross-kh partials, 8 KB

    const int tid  = threadIdx.x;
    const int wave = tid >> 6;          // 0..7
    const int jq   = wave >> 1;         // j-pair index (0..3)
    const int kh   = wave & 1;          // k-half within chunk
    const int lane = tid & 63;
    const int ks   = lane & 7;
    const int bo8  = lane >> 3;
    const int rgB  = blockIdx.x >> 1;   // j in [8*rgB, 8*rgB+8)
    const int bgB  = blockIdx.x & 1;    // b in [64*bgB, 64*bgB+64)

    // ---- stage W once, gate-interleaved (512 threads: 2 rows per pass) ----
    {
        auto stageW = [&](const float* Wsrc, int g) {
            #pragma unroll
            for (int it = 0; it < 4; ++it) {
                const int row = it * 2 + (tid >> 8);     // 0..7
                const int c4  = tid & 255;               // float4 column
                const float4 v = ld4(Wsrc + (size_t)(rgB * 8 + row) * HDIM + c4 * 4);
                sW[row][c4 * 4 + 0][g] = v.x;
                sW[row][c4 * 4 + 1][g] = v.y;
                sW[row][c4 * 4 + 2][g] = v.z;
                sW[row][c4 * 4 + 3][g] = v.w;
            }
        };
        stageW(Wgh, 0); stageW(Wih, 1); stageW(Wfh, 2); stageW(Woh, 3);
    }

    // epilogue cells (kh==0 waves): j = rgB*8 + jq*2 + (ks>>2),
    // b = bgB*64 + bo8*8 + (ks&3)*2 + {0,1}
    const int jc = rgB * 8 + jq * 2 + (ks >> 2);
    const float4 wx4 = make_float4(Wgx[jc], Wix[jc], Wfx[jc], Wox[jc]);
    const float4 b4  = make_float4(bg[jc], bi[jc], bf[jc], bo[jc]);
    float c0 = 0.f, c1 = 0.f;

    // direct-h addressing (u64 units): row = k (64 u64/row)
    const int kc0 = kh * 8 + ks;            // chunk-local k, kk=0
    const int kc1 = 16 + kh * 8 + ks;       // chunk-local k, kk=1
    const int hb  = bgB * 32 + bo8 * 4;     // b offset in u64 units
    const size_t koA = (size_t)kc0 * 64 + hb;
    const size_t koB = (size_t)kc1 * 64 + hb;

    // zero h0 (threads 0..255 of each block cover g_hx[0])
    if (tid < 256)
        astore(&g_hx[0][0][0] + (size_t)blockIdx.x * 256 + tid, 0ull);

    gbar(bar, 0);

#define CHUNK(C, CUR, NXT, PF)                                                  \
    {                                                                           \
        if (PF) {   /* issue chunk C+1 loads; consumed next CHUNK */            \
            const u64* s_ = hc + (size_t)((C) + 1) * 2048;                      \
            NXT[0] = *(const ull2*)(s_ + koA);                                  \
            NXT[1] = *(const ull2*)(s_ + koA + 2);                              \
            NXT[2] = *(const ull2*)(s_ + koB);                                  \
            NXT[3] = *(const ull2*)(s_ + koB + 2);                              \
        }                                                                       \
        {   /* kk = 0 */                                                        \
            const float4 w0 = ld4(&sW[jq * 2 + 0][(C) * 32 + kc0][0]);          \
            const float4 w1 = ld4(&sW[jq * 2 + 1][(C) * 32 + kc0][0]);          \
            const float4 hA = two2f4(CUR[0].x, CUR[0].y);                       \
            const float4 hB = two2f4(CUR[1].x, CUR[1].y);                       \
            FMA4(acc[0][0], hA.x, w0); FMA4(acc[0][1], hA.y, w0);               \
            FMA4(acc[0][2], hA.z, w0); FMA4(acc[0][3], hA.w, w0);               \
            FMA4(acc[0][4], hB.x, w0); FMA4(acc[0][5], hB.y, w0);               \
            FMA4(acc[0][6], hB.z, w0); FMA4(acc[0][7], hB.w, w0);               \
            FMA4(acc[1][0], hA.x, w1); FMA4(acc[1][1], hA.y, w1);               \
            FMA4(acc[1][2], hA.z, w1); FMA4(acc[1][3], hA.w, w1);               \
            FMA4(acc[1][4], hB.x, w1); FMA4(acc[1][5], hB.y, w1);               \
            FMA4(acc[1][6], hB.z, w1); FMA4(acc[1][7], hB.w, w1);               \
        }                                                                       \
        {   /* kk = 1 */                                                        \
            const float4 w0 = ld4(&sW[jq * 2 + 0][(C) * 32 + kc1][0]);          \
            const float4 w1 = ld4(&sW[jq * 2 + 1][(C) * 32 + kc1][0]);          \
            const float4 hA = two2f4(CUR[2].x, CUR[2].y);                       \
            const float4 hB = two2f4(CUR[3].x, CUR[3].y);                       \
            FMA4(acc[0][0], hA.x, w0); FMA4(acc[0][1], hA.y, w0);               \
            FMA4(acc[0][2], hA.z, w0); FMA4(acc[0][3], hA.w, w0);               \
            FMA4(acc[0][4], hB.x, w0); FMA4(acc[0][5], hB.y, w0);               \
            FMA4(acc[0][6], hB.z, w0); FMA4(acc[0][7], hB.w, w0);               \
            FMA4(acc[1][0], hA.x, w1); FMA4(acc[1][1], hA.y, w1);               \
            FMA4(acc[1][2], hA.z, w1); FMA4(acc[1][3], hA.w, w1);               \
            FMA4(acc[1][4], hB.x, w1); FMA4(acc[1][5], hB.y, w1);               \
            FMA4(acc[1][6], hB.z, w1); FMA4(acc[1][7], hB.w, w1);               \
        }                                                                       \
    }

    for (int t = 0; t < TLEN; ++t) {
        const u64* hc = &g_hx[t & 1][0][0];
        u64*       hn = &g_hx[(t + 1) & 1][0][0];

        // prefetch x early (consumed in epilogue; hides post-inv MALL latency)
        float xa = 0.f, xb = 0.f;
        if (kh == 0) {
            const int b0 = bgB * 64 + bo8 * 8 + (ks & 3) * 2;
            xa = x[(size_t)b0 * TLEN + t];
            xb = x[(size_t)(b0 + 1) * TLEN + t];
        }

        float4 acc[2][8];   // [j_local][b_in_octet]; components = 4 gates. STATIC indices only.
        #pragma unroll
        for (int jl = 0; jl < 2; ++jl)
            #pragma unroll
            for (int cb = 0; cb < 8; ++cb)
                acc[jl][cb] = make_float4(0.f, 0.f, 0.f, 0.f);

        ull2 A[4], B[4];
        {   // load chunk 0
            A[0] = *(const ull2*)(hc + koA);
            A[1] = *(const ull2*)(hc + koA + 2);
            A[2] = *(const ull2*)(hc + koB);
            A[3] = *(const ull2*)(hc + koB + 2);
        }

        #pragma unroll 1
        for (int cc = 0; cc < 16; ++cc) {
            CHUNK(cc * 2,     A, B, true);
            CHUNK(cc * 2 + 1, B, A, (cc < 15));
        }

        // ---- butterfly over ks (lane bits 0..2) ----
        #pragma unroll
        for (int jl = 0; jl < 2; ++jl)
            #pragma unroll
            for (int cb = 0; cb < 8; ++cb) {
                float4& v = acc[jl][cb];
                v.x += __shfl_xor(v.x, 1); v.y += __shfl_xor(v.y, 1);
                v.z += __shfl_xor(v.z, 1); v.w += __shfl_xor(v.w, 1);
                v.x += __shfl_xor(v.x, 2); v.y += __shfl_xor(v.y, 2);
                v.z += __shfl_xor(v.z, 2); v.w += __shfl_xor(v.w, 2);
                v.x += __shfl_xor(v.x, 4); v.y += __shfl_xor(v.y, 4);
                v.z += __shfl_xor(v.z, 4); v.w += __shfl_xor(v.w, 4);
            }

        // ---- select this lane's 2 cells (static indices via 8 branches) ----
        float4 q0 = make_float4(0.f, 0.f, 0.f, 0.f);
        float4 q1 = make_float4(0.f, 0.f, 0.f, 0.f);
#define SEL(K)                                                          \
        if (ks == (K)) {                                                \
            q0 = acc[(K) >> 2][((K) & 3) * 2 + 0];                      \
            q1 = acc[(K) >> 2][((K) & 3) * 2 + 1];                      \
        }
        SEL(0) SEL(1) SEL(2) SEL(3) SEL(4) SEL(5) SEL(6) SEL(7)
#undef SEL

        // ---- cross-kh reduction through LDS scratch ----
        if (kh == 1) {
            sS[jq][lane][0] = q0;
            sS[jq][lane][1] = q1;
        }
        __syncthreads();

        if (kh == 0) {
            const float4 p0 = sS[jq][lane][0];
            const float4 p1 = sS[jq][lane][1];
            q0.x += p0.x; q0.y += p0.y; q0.z += p0.z; q0.w += p0.w;
            q1.x += p1.x; q1.y += p1.y; q1.z += p1.z; q1.w += p1.w;

            FMA4(q0, xa, wx4); FMA4(q1, xb, wx4);
            q0.x += b4.x; q0.y += b4.y; q0.z += b4.z; q0.w += b4.w;
            q1.x += b4.x; q1.y += b4.y; q1.z += b4.z; q1.w += b4.w;

            const float g0 = tanhf(q0.x);
            const float i0 = 1.f / (1.f + expf(-q0.y));
            const float f0 = 1.f / (1.f + expf(-q0.z));
            const float o0 = 1.f / (1.f + expf(-q0.w));
            c0 = g0 * i0 + c0 * f0;
            const float hv0 = tanhf(c0) * o0;

            const float g1 = tanhf(q1.x);
            const float i1 = 1.f / (1.f + expf(-q1.y));
            const float f1 = 1.f / (1.f + expf(-q1.z));
            const float o1 = 1.f / (1.f + expf(-q1.w));
            c1 = g1 * i1 + c1 * f1;
            const float hv1 = tanhf(c1) * o1;

            astore(hn + (size_t)jc * 64 + bgB * 32 + bo8 * 4 + (ks & 3),
                   f2toU(hv0, hv1));
        }

        gbar(bar, t + 1);
    } // t
#undef CHUNK

    // ---- final projection: out = h_final @ W_ph + bias_p (final h in buf 0) ----
    if (blockIdx.x < BATCH) {
        const int b = blockIdx.x;
        float part[CDIM];
        #pragma unroll
        for (int c2 = 0; c2 < CDIM; ++c2) part[c2] = 0.f;
        for (int k = tid; k < HDIM; k += NT) {
            const float2 hv2 = u2f2(g_hx[0][k][b >> 1]);   // post-gbar: fresh
            const float hvv = (b & 1) ? hv2.y : hv2.x;
            #pragma unroll
            for (int c2 = 0; c2 < CDIM; ++c2)
                part[c2] = fmaf(hvv, Wph[(size_t)k * CDIM + c2], part[c2]);
        }
        float* red = (float*)&sW[0][0][0];   // reuse dead W LDS (24 KB needed)
        #pragma unroll
        for (int c2 = 0; c2 < CDIM; ++c2) red[tid * 12 + c2] = part[c2];
        __syncthreads();
        for (int s = NT / 2; s > 0; s >>= 1) {
            if (tid < s) {
                #pragma unroll
                for (int c2 = 0; c2 < CDIM; ++c2)
                    red[tid * 12 + c2] += red[(tid + s) * 12 + c2];
            }
            __syncthreads();
        }
        if (tid < CDIM) out[(size_t)b * CDIM + tid] = red[tid] + bp[tid];
    }
}

extern "C" void kernel_launch(void* const* d_in, const int* in_sizes, int n_in,
                              void* d_out, int out_size, void* d_ws, size_t ws_size,
                              hipStream_t stream) {
    const float* x   = (const float*)d_in[0];
    const float* Wgx = (const float*)d_in[1];
    const float* Wgh = (const float*)d_in[2];
    const float* bg  = (const float*)d_in[3];
    const float* Wix = (const float*)d_in[4];
    const float* Wih = (const float*)d_in[5];
    const float* bi  = (const float*)d_in[6];
    const float* Wfx = (const float*)d_in[7];
    const float* Wfh = (const float*)d_in[8];
    const float* bf  = (const float*)d_in[9];
    const float* Wox = (const float*)d_in[10];
    const float* Woh = (const float*)d_in[11];
    const float* bo  = (const float*)d_in[12];
    const float* Wph = (const float*)d_in[13];
    const float* bp  = (const float*)d_in[14];
    u32* bar = (u32*)d_ws;                 // TLEN+2 barrier slots
    float* out = (float*)d_out;

    hipMemsetAsync(d_ws, 0, (TLEN + 2) * sizeof(u32), stream);   // capturable node

    void* args[] = {&x, &Wgx, &Wgh, &bg, &Wix, &Wih, &bi, &Wfx, &Wfh, &bf,
                    &Wox, &Woh, &bo, &Wph, &bp, &bar, &out};
    hipError_t rc = hipLaunchCooperativeKernel((void*)lstm_fused, dim3(NWG), dim3(NT),
                                               args, 0, stream);
    if (rc != hipSuccess) {
        // Custom barrier needs no cooperative-runtime support; 256 blocks at
        // 1 block/CU are fully co-resident under a regular launch too.
        lstm_fused<<<dim3(NWG), dim3(NT), 0, stream>>>(
            x, Wgx, Wgh, bg, Wix, Wih, bi, Wfx, Wfh, bf,
            Wox, Woh, bo, Wph, bp, bar, out);
    }
}

// Round 11
// 8623.100 us; speedup vs baseline: 1.6145x; 1.6145x over previous
//
#include <hip/hip_runtime.h>
#include <cmath>

#define BATCH 128
#define TLEN  256
#define HDIM  1024
#define CDIM  10
#define NT    512
#define NWG   256

typedef unsigned long long u64;
typedef unsigned int u32;

// h state, double buffered, k-major, u64 = 2 packed floats: g_hx[buf][j][b/2].
// ALL h accesses are relaxed agent-scope atomics (sc1: bypass non-coherent
// per-XCD L2) -> no cache-maintenance fences anywhere; x/W/bias lines stay
// warm in L1/L2 across all 256 steps (round-7 A/B: sc1 == cached+inv perf).
__device__ u64 g_hx[2][HDIM][BATCH / 2];

__device__ __forceinline__ float4 ld4(const float* p) { return *(const float4*)p; }

__device__ __forceinline__ u64 aload(const u64* p) {
    return __hip_atomic_load(p, __ATOMIC_RELAXED, __HIP_MEMORY_SCOPE_AGENT);
}
__device__ __forceinline__ void astore(u64* p, u64 v) {
    __hip_atomic_store(p, v, __ATOMIC_RELAXED, __HIP_MEMORY_SCOPE_AGENT);
}
__device__ __forceinline__ void astore32(u32* p, u32 v) {
    __hip_atomic_store(p, v, __ATOMIC_RELAXED, __HIP_MEMORY_SCOPE_AGENT);
}
__device__ __forceinline__ float4 two2f4(u64 a, u64 b) {
    u64 t[2] = {a, b}; float4 f; __builtin_memcpy(&f, t, 16); return f;
}
__device__ __forceinline__ u64 f2toU(float a, float b) {
    float2 f = make_float2(a, b); u64 v; __builtin_memcpy(&v, &f, 8); return v;
}
__device__ __forceinline__ float2 u2f2(u64 v) {
    float2 f; __builtin_memcpy(&f, &v, 8); return f;
}

// Group barrier (128 blocks sharing one b-half), parallel arrivals:
// per-wave vmcnt drain (sc1 h-stores at MALL) -> block sync -> thread0
// sc1-stores flags[grp][rgB]=target (128 distinct addresses, no RMW convoy)
// -> every wave polls lane-parallel (1 u64 covers 2 flags; __all) and
// self-releases. Monotonic targets -> no reset. Bounded spin -> no hangs.
// GROUP-CONFINEMENT INVARIANT (round-10 lesson: two cross-group races):
// every datum a block touches between barriers must be produced by its OWN
// group -- recurrence reads/writes + x + h0-zeroing + final projection all
// stay inside the block's b-half.
__device__ __forceinline__ void gbar2(u32* flags, int grp, int idx, u32 target) {
    asm volatile("s_waitcnt vmcnt(0)" ::: "memory");
    __syncthreads();
    if (threadIdx.x == 0)
        astore32(flags + grp * 128 + idx, target);
    const u64* base = (const u64*)(flags + grp * 128) + (threadIdx.x & 63);
    int guard = 0;
    for (;;) {
        const u64 v = aload(base);
        const bool ok = ((u32)v >= target) && ((u32)(v >> 32) >= target);
        if (__all(ok) || ++guard > (1 << 20)) break;
        __builtin_amdgcn_s_sleep(1);
    }
}

#define FMA4(d, s, v) do { (d).x = fmaf((s), (v).x, (d).x); (d).y = fmaf((s), (v).y, (d).y); \
                           (d).z = fmaf((s), (v).z, (d).z); (d).w = fmaf((s), (v).w, (d).w); } while (0)

// Block: 8 j x 64 b. 8 waves: wave = jq*2 + kh; k-subset {c*32 + kk*16 + kh*8 + ks}.
// R8-proven body: LDS-staged h (512-thread cooperative, high MLP), per-chunk
// __syncthreads, intra-wave ks-butterfly + cross-kh LDS exchange. Gates in
// float4 components; ALL register indices static (round-3 scratch lesson).
__global__ void __launch_bounds__(NT, 1)
lstm_fused(const float* __restrict__ x,
           const float* __restrict__ Wgx, const float* __restrict__ Wgh, const float* __restrict__ bg,
           const float* __restrict__ Wix, const float* __restrict__ Wih, const float* __restrict__ bi,
           const float* __restrict__ Wfx, const float* __restrict__ Wfh, const float* __restrict__ bf,
           const float* __restrict__ Wox, const float* __restrict__ Woh, const float* __restrict__ bo,
           const float* __restrict__ Wph, const float* __restrict__ bp,
           u32* __restrict__ flags, float* __restrict__ out)
{
    __shared__ float  sW[8][HDIM][4];   // [j_local][k][gate], 128 KB, persistent
    __shared__ float  sH[2][32][68];    // [buf][k_chunk][b_local], 17 KB
    __shared__ float4 sS[4][64][2];     // cross-kh partials, 8 KB
    __shared__ float  sX[64];

    const int tid  = threadIdx.x;
    const int wave = tid >> 6;          // 0..7
    const int jq   = wave >> 1;         // j-pair index (0..3)
    const int kh   = wave & 1;          // k-half within chunk
    const int lane = tid & 63;
    const int ks   = lane & 7;
    const int bo8  = lane >> 3;
    const int rgB  = blockIdx.x >> 1;   // j in [8*rgB, 8*rgB+8)  == index in group
    const int bgB  = blockIdx.x & 1;    // b in [64*bgB, 64*bgB+64) == group id

    // ---- stage W once, gate-interleaved (512 threads: 2 rows per pass) ----
    {
        auto stageW = [&](const float* Wsrc, int g) {
            #pragma unroll
            for (int it = 0; it < 4; ++it) {
                const int row = it * 2 + (tid >> 8);     // 0..7
                const int c4  = tid & 255;               // float4 column
                const float4 v = ld4(Wsrc + (size_t)(rgB * 8 + row) * HDIM + c4 * 4);
                sW[row][c4 * 4 + 0][g] = v.x;
                sW[row][c4 * 4 + 1][g] = v.y;
                sW[row][c4 * 4 + 2][g] = v.z;
                sW[row][c4 * 4 + 3][g] = v.w;
            }
        };
        stageW(Wgh, 0); stageW(Wih, 1); stageW(Wfh, 2); stageW(Woh, 3);
    }

    // epilogue cells (kh==0 waves): j = rgB*8 + jq*2 + (ks>>2),
    // b = bgB*64 + bo8*8 + (ks&3)*2 + {0,1}
    const int jc = rgB * 8 + jq * 2 + (ks >> 2);
    const float4 wx4 = make_float4(Wgx[jc], Wix[jc], Wfx[jc], Wox[jc]);
    const float4 b4  = make_float4(bg[jc], bi[jc], bf[jc], bo[jc]);
    float c0 = 0.f, c1 = 0.f;

    // zero h0 -- OWN b-half only (group-confinement): 8 j-rows x 32 u64
    if (tid < 256)
        astore(&g_hx[0][rgB * 8 + (tid >> 5)][bgB * 32 + (tid & 31)], 0ull);

    gbar2(flags, bgB, rgB, 1u);

    const int skc = tid >> 4;                   // staging: k within chunk (0..31)
    const int sb  = (tid & 15) * 4;             // staging: b offset in floats
    const int hb0 = bgB * 32 + (tid & 15) * 2;  // staging: b offset in u64 units

    for (int t = 0; t < TLEN; ++t) {
        const u64* hc = &g_hx[t & 1][0][0];
        u64*       hn = &g_hx[(t + 1) & 1][0][0];

        if (tid < 64) sX[tid] = x[(size_t)(bgB * 64 + tid) * TLEN + t];
        {   // stage h chunk 0 (sc1 loads -> MALL-fresh)
            const u64* src = hc + (size_t)skc * 64 + hb0;
            *(float4*)&sH[0][skc][sb] = two2f4(aload(src), aload(src + 1));
        }
        __syncthreads();

        float4 acc[2][8];   // [j_local][b_in_octet]; components = 4 gates. STATIC indices only.
        #pragma unroll
        for (int jl = 0; jl < 2; ++jl)
            #pragma unroll
            for (int cb = 0; cb < 8; ++cb)
                acc[jl][cb] = make_float4(0.f, 0.f, 0.f, 0.f);

        #pragma unroll 1
        for (int c = 0; c < 32; ++c) {
            const int buf = c & 1;
            u64 q0, q1;
            if (c < 31) {   // global->reg prefetch of chunk c+1 (sc1)
                const u64* src = hc + (size_t)((c + 1) * 32 + skc) * 64 + hb0;
                q0 = aload(src); q1 = aload(src + 1);
            }
            #pragma unroll
            for (int kk = 0; kk < 2; ++kk) {
                const int kc = kk * 16 + kh * 8 + ks;
                const float4 w0 = ld4(&sW[jq * 2 + 0][c * 32 + kc][0]);
                const float4 w1 = ld4(&sW[jq * 2 + 1][c * 32 + kc][0]);
                const float4 hA = ld4(&sH[buf][kc][bo8 * 8]);
                const float4 hB = ld4(&sH[buf][kc][bo8 * 8 + 4]);
                FMA4(acc[0][0], hA.x, w0); FMA4(acc[0][1], hA.y, w0);
                FMA4(acc[0][2], hA.z, w0); FMA4(acc[0][3], hA.w, w0);
                FMA4(acc[0][4], hB.x, w0); FMA4(acc[0][5], hB.y, w0);
                FMA4(acc[0][6], hB.z, w0); FMA4(acc[0][7], hB.w, w0);
                FMA4(acc[1][0], hA.x, w1); FMA4(acc[1][1], hA.y, w1);
                FMA4(acc[1][2], hA.z, w1); FMA4(acc[1][3], hA.w, w1);
                FMA4(acc[1][4], hB.x, w1); FMA4(acc[1][5], hB.y, w1);
                FMA4(acc[1][6], hB.z, w1); FMA4(acc[1][7], hB.w, w1);
            }
            if (c < 31) {   // reg->LDS for chunk c+1
                *(float4*)&sH[buf ^ 1][skc][sb] = two2f4(q0, q1);
            }
            __syncthreads();
        }

        // ---- butterfly over ks (lane bits 0..2) ----
        #pragma unroll
        for (int jl = 0; jl < 2; ++jl)
            #pragma unroll
            for (int cb = 0; cb < 8; ++cb) {
                float4& v = acc[jl][cb];
                v.x += __shfl_xor(v.x, 1); v.y += __shfl_xor(v.y, 1);
                v.z += __shfl_xor(v.z, 1); v.w += __shfl_xor(v.w, 1);
                v.x += __shfl_xor(v.x, 2); v.y += __shfl_xor(v.y, 2);
                v.z += __shfl_xor(v.z, 2); v.w += __shfl_xor(v.w, 2);
                v.x += __shfl_xor(v.x, 4); v.y += __shfl_xor(v.y, 4);
                v.z += __shfl_xor(v.z, 4); v.w += __shfl_xor(v.w, 4);
            }

        // ---- select this lane's 2 cells (static indices via 8 branches) ----
        float4 q0 = make_float4(0.f, 0.f, 0.f, 0.f);
        float4 q1 = make_float4(0.f, 0.f, 0.f, 0.f);
#define SEL(K)                                                          \
        if (ks == (K)) {                                                \
            q0 = acc[(K) >> 2][((K) & 3) * 2 + 0];                      \
            q1 = acc[(K) >> 2][((K) & 3) * 2 + 1];                      \
        }
        SEL(0) SEL(1) SEL(2) SEL(3) SEL(4) SEL(5) SEL(6) SEL(7)
#undef SEL

        // ---- cross-kh reduction through LDS scratch ----
        if (kh == 1) {
            sS[jq][lane][0] = q0;
            sS[jq][lane][1] = q1;
        }
        __syncthreads();

        if (kh == 0) {
            const float4 p0 = sS[jq][lane][0];
            const float4 p1 = sS[jq][lane][1];
            q0.x += p0.x; q0.y += p0.y; q0.z += p0.z; q0.w += p0.w;
            q1.x += p1.x; q1.y += p1.y; q1.z += p1.z; q1.w += p1.w;

            const int cbK = (ks & 3) * 2;
            const float xa = sX[bo8 * 8 + cbK];
            const float xb = sX[bo8 * 8 + cbK + 1];
            FMA4(q0, xa, wx4); FMA4(q1, xb, wx4);
            q0.x += b4.x; q0.y += b4.y; q0.z += b4.z; q0.w += b4.w;
            q1.x += b4.x; q1.y += b4.y; q1.z += b4.z; q1.w += b4.w;

            const float g0 = tanhf(q0.x);
            const float i0 = 1.f / (1.f + expf(-q0.y));
            const float f0 = 1.f / (1.f + expf(-q0.z));
            const float o0 = 1.f / (1.f + expf(-q0.w));
            c0 = g0 * i0 + c0 * f0;
            const float hv0 = tanhf(c0) * o0;

            const float g1 = tanhf(q1.x);
            const float i1 = 1.f / (1.f + expf(-q1.y));
            const float f1 = 1.f / (1.f + expf(-q1.z));
            const float o1 = 1.f / (1.f + expf(-q1.w));
            c1 = g1 * i1 + c1 * f1;
            const float hv1 = tanhf(c1) * o1;

            astore(hn + (size_t)jc * 64 + bgB * 32 + bo8 * 4 + (ks & 3),
                   f2toU(hv0, hv1));
        }

        gbar2(flags, bgB, rgB, (u32)(t + 2));
    } // t

    // ---- final projection: out = h_final @ W_ph + bias_p (final h in buf 0).
    // Group-confinement: block projects b = bgB*64 + rgB -- a batch column in
    // its OWN group's b-half, so its own group's final barrier suffices.
    // h read sc1 (no inv anywhere -> cached h copies may be stale).
    if (rgB < 64) {
        const int b = bgB * 64 + rgB;
        float part[CDIM];
        #pragma unroll
        for (int c2 = 0; c2 < CDIM; ++c2) part[c2] = 0.f;
        for (int k = tid; k < HDIM; k += NT) {
            const float2 hv2 = u2f2(aload(&g_hx[0][k][b >> 1]));
            const float hvv = (b & 1) ? hv2.y : hv2.x;
            #pragma unroll
            for (int c2 = 0; c2 < CDIM; ++c2)
                part[c2] = fmaf(hvv, Wph[(size_t)k * CDIM + c2], part[c2]);
        }
        float* red = (float*)&sW[0][0][0];   // reuse dead W LDS (24 KB needed)
        #pragma unroll
        for (int c2 = 0; c2 < CDIM; ++c2) red[tid * 12 + c2] = part[c2];
        __syncthreads();
        for (int s = NT / 2; s > 0; s >>= 1) {
            if (tid < s) {
                #pragma unroll
                for (int c2 = 0; c2 < CDIM; ++c2)
                    red[tid * 12 + c2] += red[(tid + s) * 12 + c2];
            }
            __syncthreads();
        }
        if (tid < CDIM) out[(size_t)b * CDIM + tid] = red[tid] + bp[tid];
    }
}

extern "C" void kernel_launch(void* const* d_in, const int* in_sizes, int n_in,
                              void* d_out, int out_size, void* d_ws, size_t ws_size,
                              hipStream_t stream) {
    const float* x   = (const float*)d_in[0];
    const float* Wgx = (const float*)d_in[1];
    const float* Wgh = (const float*)d_in[2];
    const float* bg  = (const float*)d_in[3];
    const float* Wix = (const float*)d_in[4];
    const float* Wih = (const float*)d_in[5];
    const float* bi  = (const float*)d_in[6];
    const float* Wfx = (const float*)d_in[7];
    const float* Wfh = (const float*)d_in[8];
    const float* bf  = (const float*)d_in[9];
    const float* Wox = (const float*)d_in[10];
    const float* Woh = (const float*)d_in[11];
    const float* bo  = (const float*)d_in[12];
    const float* Wph = (const float*)d_in[13];
    const float* bp  = (const float*)d_in[14];
    u32* flags = (u32*)d_ws;               // u32[2][128] monotonic arrival flags
    float* out = (float*)d_out;

    hipMemsetAsync(d_ws, 0, 2 * 128 * sizeof(u32), stream);   // capturable node

    void* args[] = {&x, &Wgx, &Wgh, &bg, &Wix, &Wih, &bi, &Wfx, &Wfh, &bf,
                    &Wox, &Woh, &bo, &Wph, &bp, &flags, &out};
    hipError_t rc = hipLaunchCooperativeKernel((void*)lstm_fused, dim3(NWG), dim3(NT),
                                               args, 0, stream);
    if (rc != hipSuccess) {
        // Custom barrier needs no cooperative-runtime support; 256 blocks at
        // 1 block/CU are fully co-resident under a regular launch too.
        lstm_fused<<<dim3(NWG), dim3(NT), 0, stream>>>(
            x, Wgx, Wgh, bg, Wix, Wih, bi, Wfx, Wfh, bf,
            Wox, Woh, bo, Wph, bp, flags, out);
    }
}

// Round 12
// 6893.993 us; speedup vs baseline: 2.0194x; 1.2508x over previous
//
#include <hip/hip_runtime.h>
#include <cmath>

#define BATCH 128
#define TLEN  256
#define HDIM  1024
#define CDIM  10
#define NT    512
#define NWG   256

typedef unsigned long long u64;
typedef unsigned int u32;

// h state, double buffered, k-major, u64 = 2 packed floats: g_hx[buf][j][b/2].
// ALL h accesses are relaxed agent-scope atomics (sc1: bypass non-coherent
// per-XCD L2) -> no cache-maintenance fences anywhere; x/W/bias lines stay
// warm in L1/L2 across all 256 steps (round-7 A/B: sc1 == cached+inv perf).
__device__ u64 g_hx[2][HDIM][BATCH / 2];

__device__ __forceinline__ float4 ld4(const float* p) { return *(const float4*)p; }

__device__ __forceinline__ u64 aload(const u64* p) {
    return __hip_atomic_load(p, __ATOMIC_RELAXED, __HIP_MEMORY_SCOPE_AGENT);
}
__device__ __forceinline__ void astore(u64* p, u64 v) {
    __hip_atomic_store(p, v, __ATOMIC_RELAXED, __HIP_MEMORY_SCOPE_AGENT);
}
__device__ __forceinline__ void astore32(u32* p, u32 v) {
    __hip_atomic_store(p, v, __ATOMIC_RELAXED, __HIP_MEMORY_SCOPE_AGENT);
}
__device__ __forceinline__ float4 two2f4(u64 a, u64 b) {
    u64 t[2] = {a, b}; float4 f; __builtin_memcpy(&f, t, 16); return f;
}
__device__ __forceinline__ u64 f2toU(float a, float b) {
    float2 f = make_float2(a, b); u64 v; __builtin_memcpy(&v, &f, 8); return v;
}
__device__ __forceinline__ float2 u2f2(u64 v) {
    float2 f; __builtin_memcpy(&f, &v, 8); return f;
}

// Group barrier (128 blocks sharing one b-half), parallel arrivals (R11-proven):
// per-wave vmcnt drain -> block sync -> thread0 sc1-stores flags[grp][rgB] =
// target (128 distinct addresses, no RMW convoy) -> every wave polls
// lane-parallel and self-releases. Monotonic targets; bounded spin.
// GROUP-CONFINEMENT INVARIANT (round-10 lesson): every datum a block touches
// between barriers is produced by its OWN group (recurrence, x, h0-zeroing,
// final projection all stay inside the block's b-half).
__device__ __forceinline__ void gbar2(u32* flags, int grp, int idx, u32 target) {
    asm volatile("s_waitcnt vmcnt(0)" ::: "memory");
    __syncthreads();
    if (threadIdx.x == 0)
        astore32(flags + grp * 128 + idx, target);
    const u64* base = (const u64*)(flags + grp * 128) + (threadIdx.x & 63);
    int guard = 0;
    for (;;) {
        const u64 v = aload(base);
        const bool ok = ((u32)v >= target) && ((u32)(v >> 32) >= target);
        if (__all(ok) || ++guard > (1 << 20)) break;
        __builtin_amdgcn_s_sleep(1);
    }
}

#define FMA4(d, s, v) do { (d).x = fmaf((s), (v).x, (d).x); (d).y = fmaf((s), (v).y, (d).y); \
                           (d).z = fmaf((s), (v).z, (d).z); (d).w = fmaf((s), (v).w, (d).w); } while (0)

// Block: 8 j x 64 b. 8 waves: wave = jq*2 + kh; k-subset {c*32 + kk*16 + kh*8 + ks}.
// R11 body + DEPTH-2 h prefetch: load for chunk c+3 issued at chunk c (two
// static register sets QA/QB via manual 2x unroll), so the staging write's
// vmcnt wait has ~2 chunk-times of cover (MALL latency ~600-900 cyc vs ~500
// cyc per chunk at depth-1 -- the round-11 residual stall).
__global__ void __launch_bounds__(NT, 1)
lstm_fused(const float* __restrict__ x,
           const float* __restrict__ Wgx, const float* __restrict__ Wgh, const float* __restrict__ bg,
           const float* __restrict__ Wix, const float* __restrict__ Wih, const float* __restrict__ bi,
           const float* __restrict__ Wfx, const float* __restrict__ Wfh, const float* __restrict__ bf,
           const float* __restrict__ Wox, const float* __restrict__ Woh, const float* __restrict__ bo,
           const float* __restrict__ Wph, const float* __restrict__ bp,
           u32* __restrict__ flags, float* __restrict__ out)
{
    __shared__ float  sW[8][HDIM][4];   // [j_local][k][gate], 128 KB, persistent
    __shared__ float  sH[2][32][68];    // [buf][k_chunk][b_local], 17 KB
    __shared__ float4 sS[4][64][2];     // cross-kh partials, 8 KB

    const int tid  = threadIdx.x;
    const int wave = tid >> 6;          // 0..7
    const int jq   = wave >> 1;         // j-pair index (0..3)
    const int kh   = wave & 1;          // k-half within chunk
    const int lane = tid & 63;
    const int ks   = lane & 7;
    const int bo8  = lane >> 3;
    const int rgB  = blockIdx.x >> 1;   // j in [8*rgB, 8*rgB+8)  == index in group
    const int bgB  = blockIdx.x & 1;    // b in [64*bgB, 64*bgB+64) == group id

    // ---- stage W once, gate-interleaved (512 threads: 2 rows per pass) ----
    {
        auto stageW = [&](const float* Wsrc, int g) {
            #pragma unroll
            for (int it = 0; it < 4; ++it) {
                const int row = it * 2 + (tid >> 8);     // 0..7
                const int c4  = tid & 255;               // float4 column
                const float4 v = ld4(Wsrc + (size_t)(rgB * 8 + row) * HDIM + c4 * 4);
                sW[row][c4 * 4 + 0][g] = v.x;
                sW[row][c4 * 4 + 1][g] = v.y;
                sW[row][c4 * 4 + 2][g] = v.z;
                sW[row][c4 * 4 + 3][g] = v.w;
            }
        };
        stageW(Wgh, 0); stageW(Wih, 1); stageW(Wfh, 2); stageW(Woh, 3);
    }

    // epilogue cells (kh==0 waves): j = rgB*8 + jq*2 + (ks>>2),
    // b = bgB*64 + bo8*8 + (ks&3)*2 + {0,1}
    const int jc = rgB * 8 + jq * 2 + (ks >> 2);
    const float4 wx4 = make_float4(Wgx[jc], Wix[jc], Wfx[jc], Wox[jc]);
    const float4 b4  = make_float4(bg[jc], bi[jc], bf[jc], bo[jc]);
    float c0 = 0.f, c1 = 0.f;

    // zero h0 -- OWN b-half only (group-confinement): 8 j-rows x 32 u64
    if (tid < 256)
        astore(&g_hx[0][rgB * 8 + (tid >> 5)][bgB * 32 + (tid & 31)], 0ull);

    gbar2(flags, bgB, rgB, 1u);

    const int skc = tid >> 4;                   // staging: k within chunk (0..31)
    const int sb  = (tid & 15) * 4;             // staging: b offset in floats
    const int hb0 = bgB * 32 + (tid & 15) * 2;  // staging: b offset in u64 units
    const int xb0 = bgB * 64 + bo8 * 8 + (ks & 3) * 2;   // epilogue batch base

#define COMP(C, BUF)                                                            \
    {                                                                           \
        _Pragma("unroll")                                                       \
        for (int kk = 0; kk < 2; ++kk) {                                        \
            const int kc = kk * 16 + kh * 8 + ks;                               \
            const float4 w0 = ld4(&sW[jq * 2 + 0][(C) * 32 + kc][0]);           \
            const float4 w1 = ld4(&sW[jq * 2 + 1][(C) * 32 + kc][0]);           \
            const float4 hA = ld4(&sH[BUF][kc][bo8 * 8]);                       \
            const float4 hB = ld4(&sH[BUF][kc][bo8 * 8 + 4]);                   \
            FMA4(acc[0][0], hA.x, w0); FMA4(acc[0][1], hA.y, w0);               \
            FMA4(acc[0][2], hA.z, w0); FMA4(acc[0][3], hA.w, w0);               \
            FMA4(acc[0][4], hB.x, w0); FMA4(acc[0][5], hB.y, w0);               \
            FMA4(acc[0][6], hB.z, w0); FMA4(acc[0][7], hB.w, w0);               \
            FMA4(acc[1][0], hA.x, w1); FMA4(acc[1][1], hA.y, w1);               \
            FMA4(acc[1][2], hA.z, w1); FMA4(acc[1][3], hA.w, w1);               \
            FMA4(acc[1][4], hB.x, w1); FMA4(acc[1][5], hB.y, w1);               \
            FMA4(acc[1][6], hB.z, w1); FMA4(acc[1][7], hB.w, w1);               \
        }                                                                       \
    }

    for (int t = 0; t < TLEN; ++t) {
        const u64* hc = &g_hx[t & 1][0][0];
        u64*       hn = &g_hx[(t + 1) & 1][0][0];

        // x for epilogue, loaded early (L1-resident: line covers 16 t's)
        float xa = 0.f, xb = 0.f;
        if (kh == 0) {
            xa = x[(size_t)xb0 * TLEN + t];
            xb = x[(size_t)(xb0 + 1) * TLEN + t];
        }

        {   // stage chunk 0 -> LDS directly (once/step; exposed ~0.4 us only)
            const u64* src = hc + (size_t)skc * 64 + hb0;
            *(float4*)&sH[0][skc][sb] = two2f4(aload(src), aload(src + 1));
        }
        // prologue prefetch: chunks 1 (QA) and 2 (QB) in flight
        u64 A0, A1, B0, B1;
        {
            const u64* s1 = hc + (size_t)(32 + skc) * 64 + hb0;
            A0 = aload(s1); A1 = aload(s1 + 1);
            const u64* s2 = hc + (size_t)(64 + skc) * 64 + hb0;
            B0 = aload(s2); B1 = aload(s2 + 1);
        }
        __syncthreads();

        float4 acc[2][8];   // [j_local][b_in_octet]; components = 4 gates. STATIC indices only.
        #pragma unroll
        for (int jl = 0; jl < 2; ++jl)
            #pragma unroll
            for (int cb = 0; cb < 8; ++cb)
                acc[jl][cb] = make_float4(0.f, 0.f, 0.f, 0.f);

        #pragma unroll 1
        for (int cc = 0; cc < 16; ++cc) {
            const int c0 = cc * 2;
            const int c1 = c0 + 1;
            // even chunk: compute c0 (buf 0), write c0+1 from QA, refill QA <- c0+3
            COMP(c0, 0);
            *(float4*)&sH[1][skc][sb] = two2f4(A0, A1);          // c0+1 <= 31 always
            if (c0 + 3 < 32) {
                const u64* s_ = hc + (size_t)((c0 + 3) * 32 + skc) * 64 + hb0;
                A0 = aload(s_); A1 = aload(s_ + 1);
            }
            __syncthreads();
            // odd chunk: compute c1 (buf 1), write c1+1 from QB, refill QB <- c1+3
            COMP(c1, 1);
            if (c1 + 1 < 32)
                *(float4*)&sH[0][skc][sb] = two2f4(B0, B1);
            if (c1 + 3 < 32) {
                const u64* s_ = hc + (size_t)((c1 + 3) * 32 + skc) * 64 + hb0;
                B0 = aload(s_); B1 = aload(s_ + 1);
            }
            __syncthreads();
        }

        // ---- butterfly over ks (lane bits 0..2) ----
        #pragma unroll
        for (int jl = 0; jl < 2; ++jl)
            #pragma unroll
            for (int cb = 0; cb < 8; ++cb) {
                float4& v = acc[jl][cb];
                v.x += __shfl_xor(v.x, 1); v.y += __shfl_xor(v.y, 1);
                v.z += __shfl_xor(v.z, 1); v.w += __shfl_xor(v.w, 1);
                v.x += __shfl_xor(v.x, 2); v.y += __shfl_xor(v.y, 2);
                v.z += __shfl_xor(v.z, 2); v.w += __shfl_xor(v.w, 2);
                v.x += __shfl_xor(v.x, 4); v.y += __shfl_xor(v.y, 4);
                v.z += __shfl_xor(v.z, 4); v.w += __shfl_xor(v.w, 4);
            }

        // ---- select this lane's 2 cells (static indices via 8 branches) ----
        float4 q0 = make_float4(0.f, 0.f, 0.f, 0.f);
        float4 q1 = make_float4(0.f, 0.f, 0.f, 0.f);
#define SEL(K)                                                          \
        if (ks == (K)) {                                                \
            q0 = acc[(K) >> 2][((K) & 3) * 2 + 0];                      \
            q1 = acc[(K) >> 2][((K) & 3) * 2 + 1];                      \
        }
        SEL(0) SEL(1) SEL(2) SEL(3) SEL(4) SEL(5) SEL(6) SEL(7)
#undef SEL

        // ---- cross-kh reduction through LDS scratch ----
        if (kh == 1) {
            sS[jq][lane][0] = q0;
            sS[jq][lane][1] = q1;
        }
        __syncthreads();

        if (kh == 0) {
            const float4 p0 = sS[jq][lane][0];
            const float4 p1 = sS[jq][lane][1];
            q0.x += p0.x; q0.y += p0.y; q0.z += p0.z; q0.w += p0.w;
            q1.x += p1.x; q1.y += p1.y; q1.z += p1.z; q1.w += p1.w;

            FMA4(q0, xa, wx4); FMA4(q1, xb, wx4);
            q0.x += b4.x; q0.y += b4.y; q0.z += b4.z; q0.w += b4.w;
            q1.x += b4.x; q1.y += b4.y; q1.z += b4.z; q1.w += b4.w;

            const float g0 = tanhf(q0.x);
            const float i0 = 1.f / (1.f + expf(-q0.y));
            const float f0 = 1.f / (1.f + expf(-q0.z));
            const float o0 = 1.f / (1.f + expf(-q0.w));
            c0 = g0 * i0 + c0 * f0;
            const float hv0 = tanhf(c0) * o0;

            const float g1 = tanhf(q1.x);
            const float i1 = 1.f / (1.f + expf(-q1.y));
            const float f1 = 1.f / (1.f + expf(-q1.z));
            const float o1 = 1.f / (1.f + expf(-q1.w));
            c1 = g1 * i1 + c1 * f1;
            const float hv1 = tanhf(c1) * o1;

            astore(hn + (size_t)jc * 64 + bgB * 32 + bo8 * 4 + (ks & 3),
                   f2toU(hv0, hv1));
        }

        gbar2(flags, bgB, rgB, (u32)(t + 2));
    } // t
#undef COMP

    // ---- final projection: out = h_final @ W_ph + bias_p (final h in buf 0).
    // Group-confinement: block projects b = bgB*64 + rgB (own b-half).
    // h read sc1 (no inv anywhere -> cached h copies may be stale).
    if (rgB < 64) {
        const int b = bgB * 64 + rgB;
        float part[CDIM];
        #pragma unroll
        for (int c2 = 0; c2 < CDIM; ++c2) part[c2] = 0.f;
        for (int k = tid; k < HDIM; k += NT) {
            const float2 hv2 = u2f2(aload(&g_hx[0][k][b >> 1]));
            const float hvv = (b & 1) ? hv2.y : hv2.x;
            #pragma unroll
            for (int c2 = 0; c2 < CDIM; ++c2)
                part[c2] = fmaf(hvv, Wph[(size_t)k * CDIM + c2], part[c2]);
        }
        float* red = (float*)&sW[0][0][0];   // reuse dead W LDS (24 KB needed)
        #pragma unroll
        for (int c2 = 0; c2 < CDIM; ++c2) red[tid * 12 + c2] = part[c2];
        __syncthreads();
        for (int s = NT / 2; s > 0; s >>= 1) {
            if (tid < s) {
                #pragma unroll
                for (int c2 = 0; c2 < CDIM; ++c2)
                    red[tid * 12 + c2] += red[(tid + s) * 12 + c2];
            }
            __syncthreads();
        }
        if (tid < CDIM) out[(size_t)b * CDIM + tid] = red[tid] + bp[tid];
    }
}

extern "C" void kernel_launch(void* const* d_in, const int* in_sizes, int n_in,
                              void* d_out, int out_size, void* d_ws, size_t ws_size,
                              hipStream_t stream) {
    const float* x   = (const float*)d_in[0];
    const float* Wgx = (const float*)d_in[1];
    const float* Wgh = (const float*)d_in[2];
    const float* bg  = (const float*)d_in[3];
    const float* Wix = (const float*)d_in[4];
    const float* Wih = (const float*)d_in[5];
    const float* bi  = (const float*)d_in[6];
    const float* Wfx = (const float*)d_in[7];
    const float* Wfh = (const float*)d_in[8];
    const float* bf  = (const float*)d_in[9];
    const float* Wox = (const float*)d_in[10];
    const float* Woh = (const float*)d_in[11];
    const float* bo  = (const float*)d_in[12];
    const float* Wph = (const float*)d_in[13];
    const float* bp  = (const float*)d_in[14];
    u32* flags = (u32*)d_ws;               // u32[2][128] monotonic arrival flags
    float* out = (float*)d_out;

    hipMemsetAsync(d_ws, 0, 2 * 128 * sizeof(u32), stream);   // capturable node

    void* args[] = {&x, &Wgx, &Wgh, &bg, &Wix, &Wih, &bi, &Wfx, &Wfh, &bf,
                    &Wox, &Woh, &bo, &Wph, &bp, &flags, &out};
    hipError_t rc = hipLaunchCooperativeKernel((void*)lstm_fused, dim3(NWG), dim3(NT),
                                               args, 0, stream);
    if (rc != hipSuccess) {
        // Custom barrier needs no cooperative-runtime support; 256 blocks at
        // 1 block/CU are fully co-resident under a regular launch too.
        lstm_fused<<<dim3(NWG), dim3(NT), 0, stream>>>(
            x, Wgx, Wgh, bg, Wix, Wih, bi, Wfx, Wfh, bf,
            Wox, Woh, bo, Wph, bp, flags, out);
    }
}

// Round 13
// 6343.888 us; speedup vs baseline: 2.1946x; 1.0867x over previous
//
#include <hip/hip_runtime.h>
#include <cmath>

#define BATCH 128
#define TLEN  256
#define HDIM  1024
#define CDIM  10
#define NT    1024
#define NWG   256

typedef unsigned long long u64;
typedef unsigned int u32;

// h state, double buffered, k-major, u64 = 2 packed floats: g_hx[buf][j][b/2].
// ALL h accesses are relaxed agent-scope atomics (sc1) -> no cache fences;
// x/W/bias stay warm in L1/L2 across all 256 steps.
__device__ u64 g_hx[2][HDIM][BATCH / 2];

__device__ __forceinline__ float4 ld4(const float* p) { return *(const float4*)p; }

__device__ __forceinline__ u64 aload(const u64* p) {
    return __hip_atomic_load(p, __ATOMIC_RELAXED, __HIP_MEMORY_SCOPE_AGENT);
}
__device__ __forceinline__ void astore(u64* p, u64 v) {
    __hip_atomic_store(p, v, __ATOMIC_RELAXED, __HIP_MEMORY_SCOPE_AGENT);
}
__device__ __forceinline__ void astore32(u32* p, u32 v) {
    __hip_atomic_store(p, v, __ATOMIC_RELAXED, __HIP_MEMORY_SCOPE_AGENT);
}

// Group barrier (R11/R12-proven): parallel arrivals on 128 distinct flags,
// per-wave self-release poll, monotonic targets, bounded spin.
// GROUP-CONFINEMENT INVARIANT (R10 lesson): everything a block touches
// between barriers is produced by its OWN b-half group.
__device__ __forceinline__ void gbar2(u32* flags, int grp, int idx, u32 target) {
    asm volatile("s_waitcnt vmcnt(0)" ::: "memory");
    __syncthreads();
    if (threadIdx.x == 0)
        astore32(flags + grp * 128 + idx, target);
    const u64* base = (const u64*)(flags + grp * 128) + (threadIdx.x & 63);
    int guard = 0;
    for (;;) {
        const u64 v = aload(base);
        const bool ok = ((u32)v >= target) && ((u32)(v >> 32) >= target);
        if (__all(ok) || ++guard > (1 << 20)) break;
        __builtin_amdgcn_s_sleep(1);
    }
}

#define FMA4(d, s, v) do { (d).x = fmaf((s), (v).x, (d).x); (d).y = fmaf((s), (v).y, (d).y); \
                           (d).z = fmaf((s), (v).z, (d).z); (d).w = fmaf((s), (v).w, (d).w); } while (0)
#define ADD4(d, s)     do { (d).x += (s).x; (d).y += (s).y; (d).z += (s).z; (d).w += (s).w; } while (0)

// Block: 8 j x 64 b. 16 waves: wave = jq*4 + kh (jq: j-pair, kh: k-quarter).
// Per chunk each lane handles exactly one k (kc = kh*8 + ks) -> no kk loop.
// 4 waves/SIMD (R12 lesson: at 2 waves/SIMD pipes add instead of overlap).
// Reduction: recursive-halving shfl butterfly (56 shfl vs 192) + 2-stage
// cross-kh exchange through LDS aliased onto the dead sH buffers; epilogue
// split across kh0 (cell0) / kh2 (cell1). All register indices static.
__global__ void __launch_bounds__(NT, 1)
lstm_fused(const float* __restrict__ x,
           const float* __restrict__ Wgx, const float* __restrict__ Wgh, const float* __restrict__ bg,
           const float* __restrict__ Wix, const float* __restrict__ Wih, const float* __restrict__ bi,
           const float* __restrict__ Wfx, const float* __restrict__ Wfh, const float* __restrict__ bf,
           const float* __restrict__ Wox, const float* __restrict__ Woh, const float* __restrict__ bo,
           const float* __restrict__ Wph, const float* __restrict__ bp,
           u32* __restrict__ flags, float* __restrict__ out)
{
    __shared__ float sW[8][HDIM][4];            // [j_local][k][gate], 128 KB
    __shared__ __align__(16) float sHraw[2 * 32 * 68];   // h dbuf, 17 KB; aliased by sS after last chunk
#define SH(B, K) (&sHraw[(B) * 2176 + (K) * 68])

    const int tid  = threadIdx.x;
    const int wave = tid >> 6;          // 0..15
    const int jq   = wave >> 2;         // j-pair index (0..3)
    const int kh   = wave & 3;          // k-quarter within chunk
    const int lane = tid & 63;
    const int ks   = lane & 7;
    const int bo8  = lane >> 3;
    const int rgB  = blockIdx.x >> 1;   // j in [8*rgB, 8*rgB+8)  == index in group
    const int bgB  = blockIdx.x & 1;    // b in [64*bgB, 64*bgB+64) == group id

    // ---- stage W once, gate-interleaved (1024 threads: 4 rows per pass) ----
    {
        auto stageW = [&](const float* Wsrc, int g) {
            #pragma unroll
            for (int it = 0; it < 2; ++it) {
                const int row = it * 4 + (tid >> 8);     // 0..7
                const int c4  = tid & 255;               // float4 column
                const float4 v = ld4(Wsrc + (size_t)(rgB * 8 + row) * HDIM + c4 * 4);
                sW[row][c4 * 4 + 0][g] = v.x;
                sW[row][c4 * 4 + 1][g] = v.y;
                sW[row][c4 * 4 + 2][g] = v.z;
                sW[row][c4 * 4 + 3][g] = v.w;
            }
        };
        stageW(Wgh, 0); stageW(Wih, 1); stageW(Wfh, 2); stageW(Woh, 3);
    }

    // epilogue cells: j = rgB*8 + jq*2 + (ks>>2); b = bgB*64 + bo8*8 + (ks&3)*2 + cell.
    // kh0 wave owns cell 0, kh2 wave owns cell 1 (split epilogue).
    const int jc = rgB * 8 + jq * 2 + (ks >> 2);
    const float4 wx4 = make_float4(Wgx[jc], Wix[jc], Wfx[jc], Wox[jc]);
    const float4 b4  = make_float4(bg[jc], bi[jc], bf[jc], bo[jc]);
    const int bloc = bgB * 64 + bo8 * 8 + (ks & 3) * 2;   // cell-0 batch index
    float cst = 0.f;                                       // my cell's c-state

    // zero h0 -- OWN b-half only: 8 j-rows x 32 u64
    if (tid < 256)
        astore(&g_hx[0][rgB * 8 + (tid >> 5)][bgB * 32 + (tid & 31)], 0ull);

    gbar2(flags, bgB, rgB, 1u);

    const int skc = tid >> 5;                   // staging: k within chunk (0..31)
    const int sbu = tid & 31;                   // staging: u64 col within 32
    const int hb0 = bgB * 32 + sbu;             // staging: u64 offset in g_hx row
    // u64 index of this thread's staging slot inside a buffer
    const int swA = (0 * 2176 + 0) / 2;         // buf0 base (u64 units)
    const int swB = (1 * 2176 + 0) / 2;         // buf1 base
    const int swoff = (skc * 68) / 2 + sbu;

#define COMP(C, BUF)                                                            \
    {                                                                           \
        const int kc_ = kh * 8 + ks;                                            \
        const float4 w0 = ld4(&sW[jq * 2 + 0][(C) * 32 + kc_][0]);              \
        const float4 w1 = ld4(&sW[jq * 2 + 1][(C) * 32 + kc_][0]);              \
        const float* hr = SH(BUF, kc_);                                         \
        const float4 hA = ld4(hr + bo8 * 8);                                    \
        const float4 hB = ld4(hr + bo8 * 8 + 4);                                \
        FMA4(acc[0][0], hA.x, w0); FMA4(acc[0][1], hA.y, w0);                   \
        FMA4(acc[0][2], hA.z, w0); FMA4(acc[0][3], hA.w, w0);                   \
        FMA4(acc[0][4], hB.x, w0); FMA4(acc[0][5], hB.y, w0);                   \
        FMA4(acc[0][6], hB.z, w0); FMA4(acc[0][7], hB.w, w0);                   \
        FMA4(acc[1][0], hA.x, w1); FMA4(acc[1][1], hA.y, w1);                   \
        FMA4(acc[1][2], hA.z, w1); FMA4(acc[1][3], hA.w, w1);                   \
        FMA4(acc[1][4], hB.x, w1); FMA4(acc[1][5], hB.y, w1);                   \
        FMA4(acc[1][6], hB.z, w1); FMA4(acc[1][7], hB.w, w1);                   \
    }

    for (int t = 0; t < TLEN; ++t) {
        const u64* hc = &g_hx[t & 1][0][0];
        u32*       hn32 = (u32*)&g_hx[(t + 1) & 1][0][0];

        // x for my epilogue cell (kh0 -> b, kh2 -> b+1), L1-warm
        float xv = 0.f;
        if ((kh & 1) == 0)
            xv = x[(size_t)(bloc + (kh >> 1)) * TLEN + t];

        const u64* hrow = hc + (size_t)skc * 64 + hb0;
        {   // stage chunk 0 directly (exposed ~0.4 us once/step)
            ((u64*)sHraw)[swA + swoff] = aload(hrow);
        }
        u64 A = aload(hrow + 2048);     // chunk 1
        u64 B = aload(hrow + 4096);     // chunk 2
        __syncthreads();

        float4 acc[2][8];   // [j_local][b]; components = 4 gates. STATIC indices only.
        #pragma unroll
        for (int jl = 0; jl < 2; ++jl)
            #pragma unroll
            for (int cb = 0; cb < 8; ++cb)
                acc[jl][cb] = make_float4(0.f, 0.f, 0.f, 0.f);

        #pragma unroll 1
        for (int cc = 0; cc < 16; ++cc) {
            const int e0 = cc * 2;
            COMP(e0, 0);
            ((u64*)sHraw)[swB + swoff] = A;                  // chunk e0+1
            if (e0 + 3 < 32) A = aload(hrow + (size_t)(e0 + 3) * 2048);
            __syncthreads();
            COMP(e0 + 1, 1);
            if (e0 + 2 < 32) ((u64*)sHraw)[swA + swoff] = B; // chunk e0+2
            if (e0 + 4 < 32) B = aload(hrow + (size_t)(e0 + 4) * 2048);
            __syncthreads();
        }
        // loop-final __syncthreads: all sH reads done -> sS alias safe

        // ---- intra-wave recursive-halving reduction over ks (56 shfl) ----
        float4 r1[8];
        #pragma unroll
        for (int i = 0; i < 8; ++i) {
            const float4 fs = (ks & 4) ? acc[0][i] : acc[1][i];
            float4 fr;
            fr.x = __shfl_xor(fs.x, 4); fr.y = __shfl_xor(fs.y, 4);
            fr.z = __shfl_xor(fs.z, 4); fr.w = __shfl_xor(fs.w, 4);
            const float4 fk = (ks & 4) ? acc[1][i] : acc[0][i];
            r1[i] = make_float4(fk.x + fr.x, fk.y + fr.y, fk.z + fr.z, fk.w + fr.w);
        }
        float4 r2[4];
        #pragma unroll
        for (int i = 0; i < 4; ++i) {
            const float4 fs = (ks & 2) ? r1[i] : r1[i + 4];
            float4 fr;
            fr.x = __shfl_xor(fs.x, 2); fr.y = __shfl_xor(fs.y, 2);
            fr.z = __shfl_xor(fs.z, 2); fr.w = __shfl_xor(fs.w, 2);
            const float4 fk = (ks & 2) ? r1[i + 4] : r1[i];
            r2[i] = make_float4(fk.x + fr.x, fk.y + fr.y, fk.z + fr.z, fk.w + fr.w);
        }
        float4 q0, q1;
        {
            const float4 fs0 = (ks & 1) ? r2[0] : r2[2];
            const float4 fs1 = (ks & 1) ? r2[1] : r2[3];
            float4 fr0, fr1;
            fr0.x = __shfl_xor(fs0.x, 1); fr0.y = __shfl_xor(fs0.y, 1);
            fr0.z = __shfl_xor(fs0.z, 1); fr0.w = __shfl_xor(fs0.w, 1);
            fr1.x = __shfl_xor(fs1.x, 1); fr1.y = __shfl_xor(fs1.y, 1);
            fr1.z = __shfl_xor(fs1.z, 1); fr1.w = __shfl_xor(fs1.w, 1);
            const float4 fk0 = (ks & 1) ? r2[2] : r2[0];
            const float4 fk1 = (ks & 1) ? r2[3] : r2[1];
            q0 = make_float4(fk0.x + fr0.x, fk0.y + fr0.y, fk0.z + fr0.z, fk0.w + fr0.w);
            q1 = make_float4(fk1.x + fr1.x, fk1.y + fr1.y, fk1.z + fr1.z, fk1.w + fr1.w);
        }
        // q0,q1 = partial (this kh) preacts for cells (jc, bloc) and (jc, bloc+1)

        // ---- cross-kh reduction via LDS aliased onto dead sH ----
        float4* sS = (float4*)sHraw;    // 1024 f4 = 16 KB <= 17.4 KB
        if (kh & 1) {                   // kh1 -> slot(jq,0), kh3 -> slot(jq,1)
            const int sl = ((jq * 2 + (kh >> 1)) * 64 + lane) * 2;
            sS[sl]     = q0;
            sS[sl + 1] = q1;
        }
        __syncthreads();
        if ((kh & 1) == 0) {            // kh0 adds kh1; kh2 adds kh3
            const int sl = ((jq * 2 + (kh >> 1)) * 64 + lane) * 2;
            ADD4(q0, sS[sl]);
            ADD4(q1, sS[sl + 1]);
        }
        // stage 2: kh0 surrenders q1, kh2 surrenders q0 (each keeps its cell)
        if (kh == 0) sS[((jq * 2 + 0) * 64 + lane) * 2 + 1] = q1;
        if (kh == 2) sS[((jq * 2 + 1) * 64 + lane) * 2 + 0] = q0;
        __syncthreads();

        if ((kh & 1) == 0) {
            float4 qq;
            if (kh == 0) {
                ADD4(q0, sS[((jq * 2 + 1) * 64 + lane) * 2 + 0]);
                qq = q0;
            } else {
                ADD4(q1, sS[((jq * 2 + 0) * 64 + lane) * 2 + 1]);
                qq = q1;
            }
            FMA4(qq, xv, wx4);
            qq.x += b4.x; qq.y += b4.y; qq.z += b4.z; qq.w += b4.w;
            const float g_ = tanhf(qq.x);
            const float i_ = 1.f / (1.f + expf(-qq.y));
            const float f_ = 1.f / (1.f + expf(-qq.z));
            const float o_ = 1.f / (1.f + expf(-qq.w));
            cst = g_ * i_ + cst * f_;
            const float hv = tanhf(cst) * o_;
            u32 bits; __builtin_memcpy(&bits, &hv, 4);
            astore32(hn32 + (size_t)jc * 128 + bloc + (kh >> 1), bits);
        }

        gbar2(flags, bgB, rgB, (u32)(t + 2));
    } // t
#undef COMP

    // ---- final projection: out = h_final @ W_ph + bias_p (final h in buf 0).
    // Group-confinement: block projects b = bgB*64 + rgB (own b-half).
    // h read sc1 (no inv anywhere -> cached h copies may be stale).
    if (rgB < 64) {
        const int b = bgB * 64 + rgB;
        float part[CDIM];
        #pragma unroll
        for (int c2 = 0; c2 < CDIM; ++c2) part[c2] = 0.f;
        for (int k = tid; k < HDIM; k += NT) {
            const u64 hvu = aload(&g_hx[0][k][b >> 1]);
            float2 hv2; __builtin_memcpy(&hv2, &hvu, 8);
            const float hvv = (b & 1) ? hv2.y : hv2.x;
            #pragma unroll
            for (int c2 = 0; c2 < CDIM; ++c2)
                part[c2] = fmaf(hvv, Wph[(size_t)k * CDIM + c2], part[c2]);
        }
        float* red = (float*)&sW[0][0][0];   // reuse dead W LDS (48 KB needed)
        #pragma unroll
        for (int c2 = 0; c2 < CDIM; ++c2) red[tid * 12 + c2] = part[c2];
        __syncthreads();
        for (int s = NT / 2; s > 0; s >>= 1) {
            if (tid < s) {
                #pragma unroll
                for (int c2 = 0; c2 < CDIM; ++c2)
                    red[tid * 12 + c2] += red[(tid + s) * 12 + c2];
            }
            __syncthreads();
        }
        if (tid < CDIM) out[(size_t)b * CDIM + tid] = red[tid] + bp[tid];
    }
}

extern "C" void kernel_launch(void* const* d_in, const int* in_sizes, int n_in,
                              void* d_out, int out_size, void* d_ws, size_t ws_size,
                              hipStream_t stream) {
    const float* x   = (const float*)d_in[0];
    const float* Wgx = (const float*)d_in[1];
    const float* Wgh = (const float*)d_in[2];
    const float* bg  = (const float*)d_in[3];
    const float* Wix = (const float*)d_in[4];
    const float* Wih = (const float*)d_in[5];
    const float* bi  = (const float*)d_in[6];
    const float* Wfx = (const float*)d_in[7];
    const float* Wfh = (const float*)d_in[8];
    const float* bf  = (const float*)d_in[9];
    const float* Wox = (const float*)d_in[10];
    const float* Woh = (const float*)d_in[11];
    const float* bo  = (const float*)d_in[12];
    const float* Wph = (const float*)d_in[13];
    const float* bp  = (const float*)d_in[14];
    u32* flags = (u32*)d_ws;               // u32[2][128] monotonic arrival flags
    float* out = (float*)d_out;

    hipMemsetAsync(d_ws, 0, 2 * 128 * sizeof(u32), stream);   // capturable node

    void* args[] = {&x, &Wgx, &Wgh, &bg, &Wix, &Wih, &bi, &Wfx, &Wfh, &bf,
                    &Wox, &Woh, &bo, &Wph, &bp, &flags, &out};
    hipError_t rc = hipLaunchCooperativeKernel((void*)lstm_fused, dim3(NWG), dim3(NT),
                                               args, 0, stream);
    if (rc != hipSuccess) {
        // Custom barrier needs no cooperative-runtime support; 256 blocks at
        // 1 block/CU are fully co-resident under a regular launch too.
        lstm_fused<<<dim3(NWG), dim3(NT), 0, stream>>>(
            x, Wgx, Wgh, bg, Wix, Wih, bi, Wfx, Wfh, bf,
            Wox, Woh, bo, Wph, bp, flags, out);
    }
}